// Round 5
// baseline (4320.484 us; speedup 1.0000x reference)
//
#include <hip/hip_runtime.h>

// ---------------------------------------------------------------------------
// Correctness-anchor pipeline, fp32 outputs (reference output dtype = float32).
// Naive LDS-tiled GEMMs, 64x64 tile, 256 threads, 4x4/thread, BK=16.
// ---------------------------------------------------------------------------

// C_f32[M,1024] = A_f32[M,1024] * B_f32[1024,1024]   (QKV projection)
__global__ __launch_bounds__(256) void ngemm_qkv(const float* __restrict__ A,
                                                 const float* __restrict__ B,
                                                 float* __restrict__ C) {
  __shared__ float As[64][17];
  __shared__ float Bs[16][65];
  const int tid = threadIdx.x;
  const int r0 = blockIdx.y * 64, c0 = blockIdx.x * 64;
  const int tr = (tid >> 4) << 2, tc = (tid & 15) << 2;
  const int ar = tid >> 2,  ak = (tid & 3) << 2;   // A stage: 64 rows x 16 k
  const int bk = tid >> 4,  bc = (tid & 15) << 2;  // B stage: 16 k x 64 cols
  float acc[4][4] = {};

  for (int k0 = 0; k0 < 1024; k0 += 16) {
    float4 a4 = *(const float4*)(A + (size_t)(r0 + ar) * 1024 + (k0 + ak));
    float4 b4 = *(const float4*)(B + (size_t)(k0 + bk) * 1024 + (c0 + bc));
    As[ar][ak] = a4.x; As[ar][ak + 1] = a4.y; As[ar][ak + 2] = a4.z; As[ar][ak + 3] = a4.w;
    Bs[bk][bc] = b4.x; Bs[bk][bc + 1] = b4.y; Bs[bk][bc + 2] = b4.z; Bs[bk][bc + 3] = b4.w;
    __syncthreads();
#pragma unroll
    for (int kk = 0; kk < 16; ++kk) {
      float av[4], bv[4];
#pragma unroll
      for (int i = 0; i < 4; ++i) av[i] = As[tr + i][kk];
#pragma unroll
      for (int j = 0; j < 4; ++j) bv[j] = Bs[kk][tc + j];
#pragma unroll
      for (int i = 0; i < 4; ++i)
#pragma unroll
        for (int j = 0; j < 4; ++j) acc[i][j] = fmaf(av[i], bv[j], acc[i][j]);
    }
    __syncthreads();
  }
#pragma unroll
  for (int i = 0; i < 4; ++i)
#pragma unroll
    for (int j = 0; j < 4; ++j)
      C[(size_t)(r0 + tr + i) * 1024 + (c0 + tc + j)] = acc[i][j];
}

// S_f32[q][k] = (1/32) * sum_d Q[q][d]*K[k][d]   (fp32 Q,K from d_out)
// grid (32 kt, 32 qt, nc); upper-triangle blocks skipped (softmax masks them)
__global__ __launch_bounds__(256) void ngemm_sc(const float* __restrict__ Q,
                                                const float* __restrict__ Kt,
                                                float* __restrict__ S) {
  if (blockIdx.x > blockIdx.y) return;
  Q  += (size_t)blockIdx.z * 2097152;
  Kt += (size_t)blockIdx.z * 2097152;
  S  += (size_t)blockIdx.z * 4194304;
  __shared__ float As[64][17];
  __shared__ float Bs[64][17];
  const int tid = threadIdx.x;
  const int r0 = blockIdx.y * 64, c0 = blockIdx.x * 64;
  const int tr = (tid >> 4) << 2, tc = (tid & 15) << 2;
  const int ar = tid >> 2, ak = (tid & 3) << 2;    // 64 rows x 16 d per stage
  float acc[4][4] = {};

  for (int k0 = 0; k0 < 1024; k0 += 16) {
    float4 a4 = *(const float4*)(Q  + (size_t)(r0 + ar) * 1024 + (k0 + ak));
    float4 b4 = *(const float4*)(Kt + (size_t)(c0 + ar) * 1024 + (k0 + ak));
    As[ar][ak] = a4.x; As[ar][ak + 1] = a4.y; As[ar][ak + 2] = a4.z; As[ar][ak + 3] = a4.w;
    Bs[ar][ak] = b4.x; Bs[ar][ak + 1] = b4.y; Bs[ar][ak + 2] = b4.z; Bs[ar][ak + 3] = b4.w;
    __syncthreads();
#pragma unroll
    for (int kk = 0; kk < 16; ++kk) {
      float av[4], bv[4];
#pragma unroll
      for (int i = 0; i < 4; ++i) av[i] = As[tr + i][kk];
#pragma unroll
      for (int j = 0; j < 4; ++j) bv[j] = Bs[tc + j][kk];
#pragma unroll
      for (int i = 0; i < 4; ++i)
#pragma unroll
        for (int j = 0; j < 4; ++j) acc[i][j] = fmaf(av[i], bv[j], acc[i][j]);
    }
    __syncthreads();
  }
#pragma unroll
  for (int i = 0; i < 4; ++i)
#pragma unroll
    for (int j = 0; j < 4; ++j)
      S[(size_t)(r0 + tr + i) * 2048 + (c0 + tc + j)] = acc[i][j] * 0.03125f;
}

// O_f32[q][d] = sum_{k<=q} P_f32[q][k] * V_f32[k][d]; grid (16 dt, 32 qt, nc)
__global__ __launch_bounds__(256) void ngemm_pv(const float* __restrict__ P,
                                                const float* __restrict__ V,
                                                float* __restrict__ C) {
  P += (size_t)blockIdx.z * 4194304;
  V += (size_t)blockIdx.z * 2097152;
  C += (size_t)blockIdx.z * 2097152;
  __shared__ float As[64][17];
  __shared__ float Bs[16][65];
  const int tid = threadIdx.x;
  const int r0 = blockIdx.y * 64, c0 = blockIdx.x * 64;
  const int tr = (tid >> 4) << 2, tc = (tid & 15) << 2;
  const int ar = tid >> 2, ak = (tid & 3) << 2;
  const int bk = tid >> 4, bc = (tid & 15) << 2;
  float acc[4][4] = {};
  const int kmax = (blockIdx.y + 1) * 64;   // causal: k <= q; diag block has P=0 above diag

  for (int k0 = 0; k0 < kmax; k0 += 16) {
    float4 a4 = *(const float4*)(P + (size_t)(r0 + ar) * 2048 + (k0 + ak));
    float4 b4 = *(const float4*)(V + (size_t)(k0 + bk) * 1024 + (c0 + bc));
    As[ar][ak] = a4.x; As[ar][ak + 1] = a4.y; As[ar][ak + 2] = a4.z; As[ar][ak + 3] = a4.w;
    Bs[bk][bc] = b4.x; Bs[bk][bc + 1] = b4.y; Bs[bk][bc + 2] = b4.z; Bs[bk][bc + 3] = b4.w;
    __syncthreads();
#pragma unroll
    for (int kk = 0; kk < 16; ++kk) {
      float av[4], bv[4];
#pragma unroll
      for (int i = 0; i < 4; ++i) av[i] = As[tr + i][kk];
#pragma unroll
      for (int j = 0; j < 4; ++j) bv[j] = Bs[kk][tc + j];
#pragma unroll
      for (int i = 0; i < 4; ++i)
#pragma unroll
        for (int j = 0; j < 4; ++j) acc[i][j] = fmaf(av[i], bv[j], acc[i][j]);
    }
    __syncthreads();
  }
#pragma unroll
  for (int i = 0; i < 4; ++i)
#pragma unroll
    for (int j = 0; j < 4; ++j)
      C[(size_t)(r0 + tr + i) * 1024 + (c0 + tc + j)] = acc[i][j];
}

// fp32 causal softmax in place, one block per row. P[j>i] = 0.
__global__ __launch_bounds__(256) void softmax_f32(float* __restrict__ S) {
  const int i = blockIdx.x;
  float* row = S + ((size_t)blockIdx.y * 2048 + (size_t)i) * 2048;
  const int tid = threadIdx.x;
  const int lane = tid & 63;
  const int wave = tid >> 6;
  const int j0 = tid * 8;

  float4 x0 = *(const float4*)(row + j0);
  float4 x1 = *(const float4*)(row + j0 + 4);
  float v[8] = {x0.x, x0.y, x0.z, x0.w, x1.x, x1.y, x1.z, x1.w};

  float m = -3.4e38f;
#pragma unroll
  for (int e = 0; e < 8; ++e)
    if (j0 + e <= i) m = fmaxf(m, v[e]);
  __shared__ float red[4];
#pragma unroll
  for (int off = 32; off; off >>= 1) m = fmaxf(m, __shfl_xor(m, off));
  if (lane == 0) red[wave] = m;
  __syncthreads();
  const float M = fmaxf(fmaxf(red[0], red[1]), fmaxf(red[2], red[3]));

  float p[8];
  float s = 0.f;
#pragma unroll
  for (int e = 0; e < 8; ++e) {
    p[e] = (j0 + e <= i) ? __expf(v[e] - M) : 0.f;
    s += p[e];
  }
#pragma unroll
  for (int off = 32; off; off >>= 1) s += __shfl_xor(s, off);
  __syncthreads();
  if (lane == 0) red[wave] = s;
  __syncthreads();
  const float inv = 1.0f / (red[0] + red[1] + red[2] + red[3]);

  float4 o0 = {p[0] * inv, p[1] * inv, p[2] * inv, p[3] * inv};
  float4 o1 = {p[4] * inv, p[5] * inv, p[6] * inv, p[7] * inv};
  *(float4*)(row + j0) = o0;
  *(float4*)(row + j0 + 4) = o1;
}

extern "C" void kernel_launch(void* const* d_in, const int* in_sizes, int n_in,
                              void* d_out, int out_size, void* d_ws, size_t ws_size,
                              hipStream_t stream) {
  const float* X  = (const float*)d_in[0];   // fp32 inputs per reference
  const float* Wq = (const float*)d_in[1];
  const float* Wk = (const float*)d_in[2];
  const float* Wv = (const float*)d_in[3];
  float* out = (float*)d_out;                // fp32 outputs [output | Q | K | V]
  float* Qo = out + 16777216;
  float* Ko = out + 2 * 16777216;
  float* Vo = out + 3 * 16777216;

  // workspace: fp32 S chunk, nc batches x 2048x2048 floats (16.8 MB each)
  float* Sb = (float*)d_ws;
  const size_t S_E = 4194304;                // floats per batch
  const size_t ws_f = ws_size / 4;
  int nc = 1;
  if      (ws_f >= 8 * S_E) nc = 8;
  else if (ws_f >= 4 * S_E) nc = 4;
  else if (ws_f >= 2 * S_E) nc = 2;

  // QKV projections (fp32 in, fp32 out)
  hipLaunchKernelGGL(ngemm_qkv, dim3(16, 256), dim3(256), 0, stream, X, Wq, Qo);
  hipLaunchKernelGGL(ngemm_qkv, dim3(16, 256), dim3(256), 0, stream, X, Wk, Ko);
  hipLaunchKernelGGL(ngemm_qkv, dim3(16, 256), dim3(256), 0, stream, X, Wv, Vo);

  // attention, nc batches at a time (fp32 S in ws)
  for (int z0 = 0; z0 < 8; z0 += nc) {
    hipLaunchKernelGGL(ngemm_sc, dim3(32, 32, nc), dim3(256), 0, stream,
                       Qo + (size_t)z0 * 2097152, Ko + (size_t)z0 * 2097152, Sb);
    hipLaunchKernelGGL(softmax_f32, dim3(2048, nc), dim3(256), 0, stream, Sb);
    hipLaunchKernelGGL(ngemm_pv, dim3(16, 32, nc), dim3(256), 0, stream,
                       Sb, Vo + (size_t)z0 * 2097152, out + (size_t)z0 * 2097152);
  }
}